// Round 4
// baseline (142.459 us; speedup 1.0000x reference)
//
#include <hip/hip_runtime.h>

// ---------- types ----------
typedef __attribute__((ext_vector_type(8))) short short8;     // 8 bf16 (4 VGPRs)
typedef __attribute__((ext_vector_type(4))) float floatx4;    // MFMA C/D & vec ld/st
typedef __attribute__((ext_vector_type(4))) unsigned int uintx4;

// ---------- fp32 -> packed bf16x2 (RNE) ----------
#if __has_builtin(__builtin_amdgcn_cvt_pk_bf16_f32)
typedef __attribute__((ext_vector_type(2))) __bf16 bf16x2;
__device__ __forceinline__ unsigned int pk_bf16(float a, float b) {
  bf16x2 v = __builtin_amdgcn_cvt_pk_bf16_f32(a, b);
  return __builtin_bit_cast(unsigned int, v);
}
#else
__device__ __forceinline__ unsigned int bf16_1(float f) {
  unsigned int u = __builtin_bit_cast(unsigned int, f);
  return (u + 0x7fffu + ((u >> 16) & 1u)) >> 16;
}
__device__ __forceinline__ unsigned int pk_bf16(float a, float b) {
  return bf16_1(a) | (bf16_1(b) << 16);
}
#endif

// Fragment conventions (verified, absmax 3.9e-3):
//   A-frag (16x16x32): lane(ln,quad) holds A[m-idx ln][k=quad*8+j], j=0..7
//   B-frag:            lane(ln,quad) holds B[col-idx ln][k=quad*8+j]
//   C/D:               col=ln, row=quad*4+reg
// Column permutation: n' = c*64 + r (c=capsule, r=route) == W's natural row
// order. Wave wv owns r in [16wv,16wv+16) and all 8 capsules as its 8
// n-fragments -> squash capsule-sum is in-register (no shuffles).
// Bprep frag id: Fb = ((mod*4 + h)*24 + ks)*8 + c; frag = 64 lanes x 16B.
// NOTE (round 3 post-mortem): NO nontemporal hints anywhere. NT stores
// amplified WRITE_SIZE 2.9x (295 MB vs 101 MB output); NT loads defeated
// cross-iteration L3 residency of the 151 MB X stream. Plain ld/st measured
// 98.7 MB writes / 86 MB fetch in the round-0 configuration.

// ============================================================
// Prepass W: [8][64][768] fp32 -> bf16 B-fragments; bias natural order.
// ============================================================
__global__ __launch_bounds__(256) void prep_w(
    const float* __restrict__ Wi, const float* __restrict__ Wc, const float* __restrict__ Wd,
    const float* __restrict__ bi, const float* __restrict__ bc, const float* __restrict__ bd,
    uintx4* __restrict__ Bprep, float* __restrict__ biasPrep) {
  const int t = blockIdx.x * 256 + threadIdx.x;  // 0 .. 147455
  const int l = t & 63;
  const int frag = t >> 6;             // 0 .. 2303 = ((mod*4+h)*24+ks)*8+c
  const int c = frag & 7;
  const int q = frag >> 3;
  const int ks = q % 24;
  const int q2 = q / 24;
  const int h = q2 & 3;
  const int mod = q2 >> 2;
  const float* __restrict__ W = (mod == 0) ? Wi : ((mod == 1) ? Wc : Wd);

  const int np = c * 64 + h * 16 + (l & 15);   // permuted col == W row index
  const int i0 = ks * 32 + (l >> 4) * 8;
  const float* src = W + (size_t)np * 768 + i0;
  floatx4 f0 = *(const floatx4*)(src);
  floatx4 f1 = *(const floatx4*)(src + 4);
  uintx4 p;
  p.x = pk_bf16(f0.x, f0.y);
  p.y = pk_bf16(f0.z, f0.w);
  p.z = pk_bf16(f1.x, f1.y);
  p.w = pk_bf16(f1.z, f1.w);
  Bprep[(size_t)frag * 64 + l] = p;

  if (t < 1536) {
    const int m2 = t >> 9;
    const float* bb = (m2 == 0) ? bi : ((m2 == 1) ? bc : bd);
    biasPrep[t] = bb[t & 511];               // natural order == n'-order
  }
}

// ============================================================
// Fused: stage A (32 x 768) once as bf16 frags in 48 KB LDS (slot-XOR),
// one barrier, register-double-buffered 24-step K-loop (2 ds_read_b128 +
// 8 L2-hot B loads + 16 MFMA per step). Epilogue: in-register squash,
// then LDS bounce (reuse A-tile) -> fully dense dwordx4 stores.
// Grid 1536 = 3 mods x 512 m-tiles (XCD-chunk swizzled); block = 4 waves.
// ============================================================
#define LOADA(aa, kk)                                                        \
  {                                                                          \
    _Pragma("unroll") for (int mt = 0; mt < 2; ++mt)                         \
        aa[mt] = Afr[((kk) * 2 + mt) * 64 +                                  \
                     ((ln ^ (((kk) * 4 + quad) & 15)) + (quad << 4))];       \
  }

#define LOADB(bb, kk)                                                        \
  {                                                                          \
    _Pragma("unroll") for (int c2 = 0; c2 < 8; ++c2)                         \
        bb[c2] = bbase[(size_t)((kk) * 8 + c2) * 64];                        \
  }

#define COMP(aa, bb)                                                     \
  {                                                                      \
    _Pragma("unroll") for (int mt = 0; mt < 2; ++mt)                     \
    {                                                                    \
      short8 af = __builtin_bit_cast(short8, aa[mt]);                    \
      _Pragma("unroll") for (int c2 = 0; c2 < 8; ++c2)                   \
          acc[mt][c2] = __builtin_amdgcn_mfma_f32_16x16x32_bf16(         \
              af, __builtin_bit_cast(short8, bb[c2]), acc[mt][c2], 0, 0, \
              0);                                                        \
    }                                                                    \
  }

__global__ __launch_bounds__(256, 3) void caps_fused(
    const float* __restrict__ x0, const float* __restrict__ x1, const float* __restrict__ x2,
    const uintx4* __restrict__ Bprep, const float* __restrict__ biasPrep,
    float* __restrict__ out) {
  __shared__ unsigned long long As64[48 * 128];  // 48 frags x 64 slots x 16 B = 48 KB

  const int tid = threadIdx.x;
  // XCD-chunk swizzle: 1536 = 8 XCDs x 192 contiguous blocks (bijective).
  // Concurrent blocks on an XCD share one mod's 768 KB B-slice -> L2-hot B.
  const int bx0 = blockIdx.x;
  const int bx = (bx0 & 7) * 192 + (bx0 >> 3);
  const int mod = bx >> 9;           // 1536 = 3 x 512
  const int bm = bx & 511;           // m-tile (32 rows)
  const float* __restrict__ X = (mod == 0) ? x0 : ((mod == 1) ? x1 : x2);

  // ---- one-shot staging: 32 rows x 768 cols fp32, coalesced ----
  const float* src = X + (size_t)bm * 32 * 768;
#pragma unroll
  for (int i = 0; i < 24; ++i) {
    const int idx = i * 1024 + tid * 4;          // flat float index in tile
    floatx4 f = *(const floatx4*)(src + idx);
    const int m = (unsigned)idx / 768u;
    const int k = idx - m * 768;
    const int ks = k >> 5;
    const int kk = k & 31;
    const int qk = kk >> 3;                      // quad of k
    const int jh = (kk >> 2) & 1;                // which 8-byte half
    const int mt = m >> 4;
    const int lnn = m & 15;
    const int p = (ks * 4 + qk) & 15;            // slot-XOR spread
    const int slot = (lnn ^ p) + (qk << 4);
    unsigned long long w =
        ((unsigned long long)pk_bf16(f.z, f.w) << 32) | pk_bf16(f.x, f.y);
    As64[(((ks * 2 + mt) * 64 + slot) << 1) + jh] = w;
  }
  __syncthreads();  // the only barrier before the epilogue

  const int lane = tid & 63;
  const int ln = lane & 15;
  const int quad = lane >> 4;
  const int wv = tid >> 6;  // wave id == h: r-range [16wv, 16wv+16)

  const uintx4* Afr = (const uintx4*)As64;
  const uintx4* bbase = Bprep + (size_t)(mod * 4 + wv) * (24 * 8 * 64) + lane;

  floatx4 acc[2][8] = {};
  uintx4 a0[2], a1[2], b0[8], b1[8];

  LOADA(a0, 0);
  LOADB(b0, 0);
#pragma unroll 1
  for (int ks2 = 0; ks2 < 12; ++ks2) {
    const int ks = 2 * ks2;
    LOADA(a1, ks + 1);
    LOADB(b1, ks + 1);
    COMP(a0, b0);
    if (ks2 != 11) {
      LOADA(a0, ks + 2);
      LOADB(b0, ks + 2);
    }
    COMP(a1, b1);
  }

  // ---- epilogue: bias + in-register squash, LDS bounce, dense stores ----
  // lane holds all 8 capsules of route r = wv*16 + ln, rows quad*4+jj (+16mt)
  const float* bp = biasPrep + mod * 512 + wv * 16 + ln;
  float bias[8];
#pragma unroll
  for (int c = 0; c < 8; ++c) bias[c] = bp[c * 64];

  float* ldsf = (float*)As64;            // reuse A-tile: 16 x 512 fp32 = 32 KB
  __syncthreads();                       // all A-frag reads complete (WAR)

#pragma unroll 1
  for (int mt = 0; mt < 2; ++mt) {
#pragma unroll
    for (int jj = 0; jj < 4; ++jj) {
      float u[8];
      float s = 0.f;
#pragma unroll
      for (int c = 0; c < 8; ++c) {
        u[c] = acc[mt][c][jj] + bias[c];
        s += u[c] * u[c];
      }
      const float sc = s / ((1.0f + s) * sqrtf(s + 1e-7f));
      floatx4 o0, o1;
      o0.x = u[0] * sc; o0.y = u[1] * sc; o0.z = u[2] * sc; o0.w = u[3] * sc;
      o1.x = u[4] * sc; o1.y = u[5] * sc; o1.z = u[6] * sc; o1.w = u[7] * sc;
      float* p = ldsf + (quad * 4 + jj) * 512 + (wv * 16 + ln) * 8;
      *(floatx4*)p = o0;
      *((floatx4*)(p + 4)) = o1;
    }
    __syncthreads();  // tile written by all waves
    // 256 threads re-read row-linearly -> 1 KiB contiguous per wave-instr
#pragma unroll
    for (int i = 0; i < 8; ++i) {
      const int idx = i * 256 + tid;         // float4 id in 16x512 tile
      const int row = idx >> 7;              // 128 float4 per row
      const int cf = (idx & 127) << 2;       // float offset in row
      const floatx4 v = *(const floatx4*)(ldsf + row * 512 + cf);
      float* gp = out + (size_t)(bm * 32 + mt * 16 + row) * 1536 + mod * 512 + cf;
      *(floatx4*)gp = v;
    }
    if (mt == 0) __syncthreads();  // WAR before second tile overwrites
  }
}

// ============================================================
extern "C" void kernel_launch(void* const* d_in, const int* in_sizes, int n_in,
                              void* d_out, int out_size, void* d_ws, size_t ws_size,
                              hipStream_t stream) {
  const float* ximg = (const float*)d_in[0];
  const float* xcapt = (const float*)d_in[1];
  const float* xdct = (const float*)d_in[2];
  const float* Wi = (const float*)d_in[3];
  const float* bi = (const float*)d_in[4];
  const float* Wc = (const float*)d_in[5];
  const float* bc = (const float*)d_in[6];
  const float* Wd = (const float*)d_in[7];
  const float* bd = (const float*)d_in[8];

  uintx4* Bprep = (uintx4*)d_ws;                           // 2.25 MiB
  float* biasPrep = (float*)((char*)d_ws + 2304 * 1024);   // 6 KiB

  hipLaunchKernelGGL(prep_w, dim3(576), dim3(256), 0, stream,
                     Wi, Wc, Wd, bi, bc, bd, Bprep, biasPrep);
  hipLaunchKernelGGL(caps_fused, dim3(1536), dim3(256), 0, stream,
                     ximg, xcapt, xdct, (const uintx4*)Bprep, biasPrep,
                     (float*)d_out);
}

// Round 5
// 95.936 us; speedup vs baseline: 1.4849x; 1.4849x over previous
//
#include <hip/hip_runtime.h>

// ---------- types ----------
typedef __attribute__((ext_vector_type(8))) short short8;     // 8 bf16 (4 VGPRs)
typedef __attribute__((ext_vector_type(4))) float floatx4;    // MFMA C/D
typedef __attribute__((ext_vector_type(4))) unsigned int uintx4;

// ---------- fp32 -> packed bf16x2 (RNE) ----------
#if __has_builtin(__builtin_amdgcn_cvt_pk_bf16_f32)
typedef __attribute__((ext_vector_type(2))) __bf16 bf16x2;
__device__ __forceinline__ unsigned int pk_bf16(float a, float b) {
  bf16x2 v = __builtin_amdgcn_cvt_pk_bf16_f32(a, b);
  return __builtin_bit_cast(unsigned int, v);
}
#else
__device__ __forceinline__ unsigned int bf16_1(float f) {
  unsigned int u = __builtin_bit_cast(unsigned int, f);
  return (u + 0x7fffu + ((u >> 16) & 1u)) >> 16;
}
__device__ __forceinline__ unsigned int pk_bf16(float a, float b) {
  return bf16_1(a) | (bf16_1(b) << 16);
}
#endif

// Fragment conventions (verified, absmax 3.9e-3):
//   A-frag (16x16x32): lane(ln,quad) holds A[m=ln][k=quad*8+j], j=0..7
//   B-frag:            lane(ln,quad) holds B[n=ln][k=quad*8+j]  (B[k][n]=W[c][r][k], n=r*8+c)
//   C/D:               col=ln, row=quad*4+reg
// Bprep frag id: Fb = ((mod*8 + h)*24 + ks)*4 + nt, n16 = h*4+nt; frag = 64 lanes x 16B.
//
// EPILOGUE / STORE PATH IS LOAD-BEARING (rounds 1-4 post-mortem):
// scalar dword stores in this exact pattern measure WRITE_SIZE = 98.7 MB
// (1.0x of the 96 MiB output). Vector float4 stores measured 1.5x and the
// LDS-bounce dense stores measured 3.0x (288 MiB exact), regardless of
// nontemporal hints; the extra write traffic also evicted X from L3
// (FETCH 86 -> 127 MB). Do NOT change the store pattern without an
// isolated A/B on WRITE_SIZE.

// ============================================================
// Prepass W: [8][64][768] fp32 -> bf16 B-fragments; bias permuted to n-order.
// ============================================================
__global__ __launch_bounds__(256) void prep_w(
    const float* __restrict__ Wi, const float* __restrict__ Wc, const float* __restrict__ Wd,
    const float* __restrict__ bi, const float* __restrict__ bc, const float* __restrict__ bd,
    uintx4* __restrict__ Bprep, float* __restrict__ biasPrep) {
  const int t = blockIdx.x * 256 + threadIdx.x;  // 0 .. 147455
  const int l = t & 63;
  const int frag = t >> 6;             // 0 .. 2303
  const int nt = frag & 3;
  const int q = frag >> 2;
  const int ks = q % 24;
  const int q2 = q / 24;
  const int h = q2 & 7;
  const int mod = q2 >> 3;
  const int n16 = h * 4 + nt;
  const float* __restrict__ W = (mod == 0) ? Wi : ((mod == 1) ? Wc : Wd);

  const int n = n16 * 16 + (l & 15);
  const int r = n >> 3;
  const int c = n & 7;
  const int i0 = ks * 32 + (l >> 4) * 8;
  const float* src = W + (size_t)(c * 64 + r) * 768 + i0;
  floatx4 f0 = *(const floatx4*)(src);
  floatx4 f1 = *(const floatx4*)(src + 4);
  uintx4 p;
  p.x = pk_bf16(f0.x, f0.y);
  p.y = pk_bf16(f0.z, f0.w);
  p.z = pk_bf16(f1.x, f1.y);
  p.w = pk_bf16(f1.z, f1.w);
  Bprep[(size_t)frag * 64 + l] = p;

  if (t < 1536) {
    const int m2 = t >> 9;
    const int nn = t & 511;
    const float* bb = (m2 == 0) ? bi : ((m2 == 1) ? bc : bd);
    biasPrep[t] = bb[(nn & 7) * 64 + (nn >> 3)];
  }
}

// ============================================================
// Fused: stage A (m=32 x K=768) ONCE as bf16 frags in LDS (48 KB, slot-XOR
// swizzled), one barrier, then a barrier-free 24-step K-loop:
// per wave-step 2 ds_read_b128 (A) + 8 L2-hot B-frag loads + 16 MFMA,
// register double-buffered. Epilogue fuses bias + squash.
// Grid 1536 = 3 mods x 512 m-tiles; block = 4 waves, wave = 32 x 128.
// ROUND 5 DELTA (the only change vs the 97.5 us round-0 kernel):
// bijective XCD-chunk swizzle so each XCD's concurrent blocks share one
// mod's ~768 KB Bprep slice -> B stays L2-resident against the X stream.
// ============================================================
#define LOADA(aa, kk)                                                        \
  {                                                                          \
    _Pragma("unroll") for (int mt = 0; mt < 2; ++mt)                         \
        aa[mt] = Afr[((kk) * 2 + mt) * 64 +                                  \
                     ((ln ^ (((kk) * 4 + quad) & 15)) + (quad << 4))];       \
  }

#define LOADB(bb, kk)                                                        \
  {                                                                          \
    _Pragma("unroll") for (int n2 = 0; n2 < 8; ++n2)                         \
        bb[n2] = bbase[(size_t)((n2 >> 2) * 96 + (kk) * 4 + (n2 & 3)) * 64]; \
  }

#define COMP(aa, bb)                                                     \
  {                                                                      \
    _Pragma("unroll") for (int mt = 0; mt < 2; ++mt)                     \
    {                                                                    \
      short8 af = __builtin_bit_cast(short8, aa[mt]);                    \
      _Pragma("unroll") for (int n2 = 0; n2 < 8; ++n2)                   \
          acc[mt][n2] = __builtin_amdgcn_mfma_f32_16x16x32_bf16(         \
              af, __builtin_bit_cast(short8, bb[n2]), acc[mt][n2], 0, 0, \
              0);                                                        \
    }                                                                    \
  }

__global__ __launch_bounds__(256, 3) void caps_fused(
    const float* __restrict__ x0, const float* __restrict__ x1, const float* __restrict__ x2,
    const uintx4* __restrict__ Bprep, const float* __restrict__ biasPrep,
    float* __restrict__ out) {
  __shared__ unsigned long long As64[48 * 128];  // 48 frags x 64 slots x 16 B

  const int tid = threadIdx.x;
  // XCD-chunk swizzle: 1536 = 8 XCDs x 192 contiguous blocks (bijective):
  // dispatcher assigns bx0 round-robin to XCDs, so XCD k sees bx in
  // [k*192, (k+1)*192) -> one mod's contiguous Bprep slice per XCD.
  const int bx0 = blockIdx.x;
  const int bx = (bx0 & 7) * 192 + (bx0 >> 3);
  const int mod = bx >> 9;           // 1536 = 3 x 512
  const int bm = bx & 511;           // m-tile (32 rows)
  const float* __restrict__ X = (mod == 0) ? x0 : ((mod == 1) ? x1 : x2);

  // ---- one-shot staging: 32 rows x 768 cols fp32, coalesced ----
  const float* src = X + (size_t)bm * 32 * 768;
#pragma unroll
  for (int i = 0; i < 24; ++i) {
    const int idx = i * 1024 + tid * 4;          // flat float index in tile
    floatx4 f = *(const floatx4*)(src + idx);
    const int m = (unsigned)idx / 768u;
    const int k = idx - m * 768;
    const int ks = k >> 5;
    const int kk = k & 31;
    const int qk = kk >> 3;                      // quad of k
    const int jh = (kk >> 2) & 1;                // which 8-byte half
    const int mt = m >> 4;
    const int lnn = m & 15;
    const int p = (ks * 4 + qk) & 15;            // slot-XOR spread
    const int slot = (lnn ^ p) + (qk << 4);
    unsigned long long w =
        ((unsigned long long)pk_bf16(f.z, f.w) << 32) | pk_bf16(f.x, f.y);
    As64[(((ks * 2 + mt) * 64 + slot) << 1) + jh] = w;
  }
  __syncthreads();  // the ONLY barrier

  const int lane = tid & 63;
  const int ln = lane & 15;
  const int quad = lane >> 4;
  const int wv = tid >> 6;  // wave id: n16-range wv*8 .. wv*8+7

  const uintx4* Afr = (const uintx4*)As64;
  const uintx4* bbase = Bprep + (size_t)((mod * 8 + wv * 2) * 24) * 4 * 64 + lane;

  floatx4 acc[2][8] = {};
  uintx4 a0[2], a1[2], b0[8], b1[8];

  LOADA(a0, 0);
  LOADB(b0, 0);
#pragma unroll 1
  for (int ks2 = 0; ks2 < 12; ++ks2) {
    const int ks = 2 * ks2;
    LOADA(a1, ks + 1);
    LOADB(b1, ks + 1);
    COMP(a0, b0);
    if (ks2 != 11) {
      LOADA(a0, ks + 2);
      LOADB(b0, ks + 2);
    }
    COMP(a1, b1);
  }

  // ---- epilogue: bias + squash (8 consecutive n cols = 8 lanes) + store ----
  const int col0 = mod * 512 + wv * 128 + ln;
  float bias[8];
#pragma unroll
  for (int n2 = 0; n2 < 8; ++n2) bias[n2] = biasPrep[col0 + n2 * 16];

#pragma unroll
  for (int mt = 0; mt < 2; ++mt) {
    const size_t rbase = (size_t)(bm * 32 + mt * 16 + quad * 4) * 1536;
#pragma unroll
    for (int n2 = 0; n2 < 8; ++n2) {
      float* op = out + rbase + col0 + n2 * 16;
#pragma unroll
      for (int jj = 0; jj < 4; ++jj) {
        float u = acc[mt][n2][jj] + bias[n2];
        float s = u * u;
        s += __shfl_xor(s, 1);
        s += __shfl_xor(s, 2);
        s += __shfl_xor(s, 4);
        float sc = s / ((1.0f + s) * sqrtf(s + 1e-7f));
        op[(size_t)jj * 1536] = u * sc;
      }
    }
  }
}

// ============================================================
extern "C" void kernel_launch(void* const* d_in, const int* in_sizes, int n_in,
                              void* d_out, int out_size, void* d_ws, size_t ws_size,
                              hipStream_t stream) {
  const float* ximg = (const float*)d_in[0];
  const float* xcapt = (const float*)d_in[1];
  const float* xdct = (const float*)d_in[2];
  const float* Wi = (const float*)d_in[3];
  const float* bi = (const float*)d_in[4];
  const float* Wc = (const float*)d_in[5];
  const float* bc = (const float*)d_in[6];
  const float* Wd = (const float*)d_in[7];
  const float* bd = (const float*)d_in[8];

  uintx4* Bprep = (uintx4*)d_ws;                           // 2.25 MiB
  float* biasPrep = (float*)((char*)d_ws + 2304 * 1024);   // 6 KiB

  hipLaunchKernelGGL(prep_w, dim3(576), dim3(256), 0, stream,
                     Wi, Wc, Wd, bi, bc, bd, Bprep, biasPrep);
  hipLaunchKernelGGL(caps_fused, dim3(1536), dim3(256), 0, stream,
                     ximg, xcapt, xdct, (const uintx4*)Bprep, biasPrep,
                     (float*)d_out);
}